// Round 1
// baseline (1834.689 us; speedup 1.0000x reference)
//
#include <hip/hip_runtime.h>

// Problem constants
static constexpr int Bc = 32, Tq = 256, Tkc = 1024, Dc = 512, Hc = 4, Pc = 512;
static constexpr float BN_EPS = 1e-5f;

// ---------------------------------------------------------------------------
// Fold eval-mode BN into the following linear layer:
//   BN(x) = x*scale + shift,  scale = gamma*rsqrt(var+eps), shift = beta - mean*scale
//   BN(x)@W^T = x @ (W*scale)^T + (shift @ W^T)
// One block per output row n. Writes Wp[n,k] = W[n,k]*scale[k], bias[n] = sum_k W[n,k]*shift[k].
// ---------------------------------------------------------------------------
__global__ __launch_bounds__(256) void fold_bn(
    const float* __restrict__ W, const float* __restrict__ gamma,
    const float* __restrict__ beta, const float* __restrict__ mean,
    const float* __restrict__ var, float* __restrict__ Wp,
    float* __restrict__ bias, int K)
{
    int n = blockIdx.x;
    int tid = threadIdx.x;
    float acc = 0.f;
    for (int k = tid; k < K; k += 256) {
        float sc = gamma[k] * rsqrtf(var[k] + BN_EPS);
        float sh = beta[k] - mean[k] * sc;
        float w = W[(long)n * K + k];
        Wp[(long)n * K + k] = w * sc;
        acc = fmaf(w, sh, acc);
    }
    __shared__ float red[256];
    red[tid] = acc;
    __syncthreads();
    for (int s = 128; s > 0; s >>= 1) {
        if (tid < s) red[tid] += red[tid + s];
        __syncthreads();
    }
    if (tid == 0) bias[n] = red[0];
}

// ---------------------------------------------------------------------------
// GEMM NT: C[m,n] = sum_k A[m,k] * B[n,k] (+ bias[n])
// A: M x K (lda), B: N x K (ldb), C: M x N (ldc). 64x64 tile, BK=16, 256 thr.
// Batched via blockIdx.z: z -> (hh = z/nB, bb = z%nB), strides per dim.
// ---------------------------------------------------------------------------
__global__ __launch_bounds__(256) void gemm_nt(
    const float* __restrict__ A, const float* __restrict__ Bm, float* __restrict__ C,
    const float* __restrict__ bias,
    int K, int lda, int ldb, int ldc,
    long sAh, long sAb, long sBb, long sCh, long sCb, int nB)
{
    int z = blockIdx.z;
    int hh = z / nB, bb = z % nB;
    A += hh * sAh + bb * sAb;
    Bm += bb * sBb;
    C += hh * sCh + bb * sCb;

    __shared__ float As[16][68];   // k-major, padded so rows are 16B-aligned
    __shared__ float Bs[16][68];

    int tid = threadIdx.x;
    int tx = tid & 15, ty = tid >> 4;
    int m0 = blockIdx.y * 64, n0 = blockIdx.x * 64;

    int lrow = tid >> 2;           // 0..63
    int lcol = (tid & 3) << 2;     // 0,4,8,12

    float acc[4][4] = {};

    for (int k0 = 0; k0 < K; k0 += 16) {
        float4 av = *(const float4*)&A[(long)(m0 + lrow) * lda + k0 + lcol];
        float4 bv = *(const float4*)&Bm[(long)(n0 + lrow) * ldb + k0 + lcol];
        __syncthreads();
        As[lcol + 0][lrow] = av.x; As[lcol + 1][lrow] = av.y;
        As[lcol + 2][lrow] = av.z; As[lcol + 3][lrow] = av.w;
        Bs[lcol + 0][lrow] = bv.x; Bs[lcol + 1][lrow] = bv.y;
        Bs[lcol + 2][lrow] = bv.z; Bs[lcol + 3][lrow] = bv.w;
        __syncthreads();
        #pragma unroll
        for (int kk = 0; kk < 16; kk++) {
            float4 a4 = *(const float4*)&As[kk][ty << 2];
            float4 b4 = *(const float4*)&Bs[kk][tx << 2];
            float ar[4] = {a4.x, a4.y, a4.z, a4.w};
            float br[4] = {b4.x, b4.y, b4.z, b4.w};
            #pragma unroll
            for (int i = 0; i < 4; i++)
                #pragma unroll
                for (int j = 0; j < 4; j++)
                    acc[i][j] = fmaf(ar[i], br[j], acc[i][j]);
        }
    }

    #pragma unroll
    for (int i = 0; i < 4; i++) {
        int m = m0 + (ty << 2) + i;
        int n = n0 + (tx << 2);
        float4 o = {acc[i][0], acc[i][1], acc[i][2], acc[i][3]};
        if (bias) {
            o.x += bias[n]; o.y += bias[n + 1]; o.z += bias[n + 2]; o.w += bias[n + 3];
        }
        *(float4*)&C[(long)m * ldc + n] = o;
    }
}

// ---------------------------------------------------------------------------
// GEMM NN: C[m,n] = sum_k A[m,k] * B[k,n]
// A: M x K (lda), B: K x N (ldb), C: M x N (ldc). Batched like gemm_nt.
// ---------------------------------------------------------------------------
__global__ __launch_bounds__(256) void gemm_nn(
    const float* __restrict__ A, const float* __restrict__ Bm, float* __restrict__ C,
    int K, int lda, int ldb, int ldc,
    long sAh, long sAb, long sBb, long sCh, long sCb, int nB)
{
    int z = blockIdx.z;
    int hh = z / nB, bb = z % nB;
    A += hh * sAh + bb * sAb;
    Bm += bb * sBb;
    C += hh * sCh + bb * sCb;

    __shared__ float As[16][68];
    __shared__ float Bs[16][68];

    int tid = threadIdx.x;
    int tx = tid & 15, ty = tid >> 4;
    int m0 = blockIdx.y * 64, n0 = blockIdx.x * 64;

    int lrow = tid >> 2;           // 0..63 (A rows)
    int lcol = (tid & 3) << 2;     // 0,4,8,12 (A k-cols)
    int bkk = tid >> 4;            // 0..15 (B k-rows)
    int bnn = (tid & 15) << 2;     // 0..60 (B n-cols)

    float acc[4][4] = {};

    for (int k0 = 0; k0 < K; k0 += 16) {
        float4 av = *(const float4*)&A[(long)(m0 + lrow) * lda + k0 + lcol];
        float4 bv = *(const float4*)&Bm[(long)(k0 + bkk) * ldb + n0 + bnn];
        __syncthreads();
        As[lcol + 0][lrow] = av.x; As[lcol + 1][lrow] = av.y;
        As[lcol + 2][lrow] = av.z; As[lcol + 3][lrow] = av.w;
        *(float4*)&Bs[bkk][bnn] = bv;
        __syncthreads();
        #pragma unroll
        for (int kk = 0; kk < 16; kk++) {
            float4 a4 = *(const float4*)&As[kk][ty << 2];
            float4 b4 = *(const float4*)&Bs[kk][tx << 2];
            float ar[4] = {a4.x, a4.y, a4.z, a4.w};
            float br[4] = {b4.x, b4.y, b4.z, b4.w};
            #pragma unroll
            for (int i = 0; i < 4; i++)
                #pragma unroll
                for (int j = 0; j < 4; j++)
                    acc[i][j] = fmaf(ar[i], br[j], acc[i][j]);
        }
    }

    #pragma unroll
    for (int i = 0; i < 4; i++) {
        int m = m0 + (ty << 2) + i;
        int n = n0 + (tx << 2);
        float4 o = {acc[i][0], acc[i][1], acc[i][2], acc[i][3]};
        *(float4*)&C[(long)m * ldc + n] = o;
    }
}

// ---------------------------------------------------------------------------
// In-place row softmax, rows of length 1024. One wave (64 lanes) per row,
// 4 rows per 256-thread block.
// ---------------------------------------------------------------------------
__global__ __launch_bounds__(256) void softmax_rows(float* __restrict__ E)
{
    int wave = threadIdx.x >> 6;
    int lane = threadIdx.x & 63;
    long row = (long)blockIdx.x * 4 + wave;
    float4* rp = (float4*)(E + row * 1024);

    float4 v[4];
    float mx = -3.4e38f;
    #pragma unroll
    for (int i = 0; i < 4; i++) {
        v[i] = rp[lane + (i << 6)];
        mx = fmaxf(mx, fmaxf(fmaxf(v[i].x, v[i].y), fmaxf(v[i].z, v[i].w)));
    }
    #pragma unroll
    for (int o = 32; o > 0; o >>= 1) mx = fmaxf(mx, __shfl_xor(mx, o, 64));

    float sum = 0.f;
    #pragma unroll
    for (int i = 0; i < 4; i++) {
        v[i].x = __expf(v[i].x - mx);
        v[i].y = __expf(v[i].y - mx);
        v[i].z = __expf(v[i].z - mx);
        v[i].w = __expf(v[i].w - mx);
        sum += v[i].x + v[i].y + v[i].z + v[i].w;
    }
    #pragma unroll
    for (int o = 32; o > 0; o >>= 1) sum += __shfl_xor(sum, o, 64);

    float inv = 1.f / sum;
    #pragma unroll
    for (int i = 0; i < 4; i++) {
        v[i].x *= inv; v[i].y *= inv; v[i].z *= inv; v[i].w *= inv;
        rp[lane + (i << 6)] = v[i];
    }
}

// ---------------------------------------------------------------------------
extern "C" void kernel_launch(void* const* d_in, const int* in_sizes, int n_in,
                              void* d_out, int out_size, void* d_ws, size_t ws_size,
                              hipStream_t stream)
{
    const float* s        = (const float*)d_in[0];
    const float* h        = (const float*)d_in[1];
    const float* phi_g    = (const float*)d_in[2];
    const float* phi_b    = (const float*)d_in[3];
    const float* phi_m    = (const float*)d_in[4];
    const float* phi_v    = (const float*)d_in[5];
    const float* W_phi    = (const float*)d_in[6];
    const float* psi_g    = (const float*)d_in[7];
    const float* psi_b    = (const float*)d_in[8];
    const float* psi_m    = (const float*)d_in[9];
    const float* psi_v    = (const float*)d_in[10];
    const float* W_psi    = (const float*)d_in[11];
    const float* red_g    = (const float*)d_in[12];
    const float* red_b    = (const float*)d_in[13];
    const float* red_m    = (const float*)d_in[14];
    const float* red_v    = (const float*)d_in[15];
    const float* W_red    = (const float*)d_in[16];

    float* out_a = (float*)d_out;                                  // (H,B,Tq,Tk)
    float* out_c = out_a + (long)Hc * Bc * Tq * Tkc;               // (B,Tq,D)

    float* ws       = (float*)d_ws;
    float* Wphi_s   = ws;                          // 2048*512
    float* Wpsi_s   = Wphi_s + 2048 * 512;         // 512*512
    float* Wred_s   = Wpsi_s + 512 * 512;          // 512*2048
    float* bias_phi = Wred_s + 512 * 2048;         // 2048
    float* bias_psi = bias_phi + 2048;             // 512
    float* bias_red = bias_psi + 512;              // 512
    float* ms       = bias_red + 512;              // 8192*2048
    float* mh       = ms + (long)8192 * 2048;      // 32768*512
    float* ctx      = mh + (long)32768 * 512;      // 8192*2048

    // 1) Fold BN into weights
    fold_bn<<<2048, 256, 0, stream>>>(W_phi, phi_g, phi_b, phi_m, phi_v, Wphi_s, bias_phi, 512);
    fold_bn<<<512,  256, 0, stream>>>(W_psi, psi_g, psi_b, psi_m, psi_v, Wpsi_s, bias_psi, 512);
    fold_bn<<<512,  256, 0, stream>>>(W_red, red_g, red_b, red_m, red_v, Wred_s, bias_red, 2048);

    // 2) ms = s @ Wphi_s^T + bias_phi   (8192 x 2048, K=512)
    gemm_nt<<<dim3(2048 / 64, 8192 / 64, 1), 256, 0, stream>>>(
        s, Wphi_s, ms, bias_phi, 512, 512, 512, 2048,
        0, 0, 0, 0, 0, 1);

    // 3) mh = h @ Wpsi_s^T + bias_psi   (32768 x 512, K=512)
    gemm_nt<<<dim3(512 / 64, 32768 / 64, 1), 256, 0, stream>>>(
        h, Wpsi_s, mh, bias_psi, 512, 512, 512, 512,
        0, 0, 0, 0, 0, 1);

    // 4) e[h,b,q,k] = ms4[b,q,h,:] . mh[b,k,:]  -> into out_a
    //    per batch z=(hh*32+bb): M=256, N=1024, K=512
    gemm_nt<<<dim3(1024 / 64, 256 / 64, Hc * Bc), 256, 0, stream>>>(
        ms, mh, out_a, nullptr, 512, 2048, 512, 1024,
        /*sAh*/ 512, /*sAb*/ (long)Tq * 2048,
        /*sBb*/ (long)Tkc * 512,
        /*sCh*/ (long)Bc * Tq * Tkc, /*sCb*/ (long)Tq * Tkc, Bc);

    // 5) softmax over k, in place (32768 rows of 1024)
    softmax_rows<<<(Hc * Bc * Tq) / 4, 256, 0, stream>>>(out_a);

    // 6) ctx[b,q,h*512+d] = sum_k a[h,b,q,k] * h[b,k,d]
    //    per batch z: M=256, N=512, K=1024  (NN flavor)
    gemm_nn<<<dim3(512 / 64, 256 / 64, Hc * Bc), 256, 0, stream>>>(
        out_a, h, ctx, 1024, 1024, 512, 2048,
        /*sAh*/ (long)Bc * Tq * Tkc, /*sAb*/ (long)Tq * Tkc,
        /*sBb*/ (long)Tkc * 512,
        /*sCh*/ 512, /*sCb*/ (long)Tq * 2048, Bc);

    // 7) c = ctx @ Wred_s^T + bias_red   (8192 x 512, K=2048)
    gemm_nt<<<dim3(512 / 64, 8192 / 64, 1), 256, 0, stream>>>(
        ctx, Wred_s, out_c, bias_red, 2048, 2048, 2048, 512,
        0, 0, 0, 0, 0, 1);
}

// Round 2
// 619.461 us; speedup vs baseline: 2.9617x; 2.9617x over previous
//
#include <hip/hip_runtime.h>

typedef short s8v __attribute__((ext_vector_type(8)));
typedef float f4v __attribute__((ext_vector_type(4)));

static constexpr int Bc = 32, Tq = 256, Tkc = 1024, Dc = 512, Hc = 4;
static constexpr float BN_EPS = 1e-5f;

__device__ inline ushort f2bf(float x) {
    union { float f; unsigned int u; } v; v.f = x;
    unsigned int r = v.u + 0x7fff + ((v.u >> 16) & 1);   // RNE
    return (ushort)(r >> 16);
}

// ---------------------------------------------------------------------------
// Fold eval-mode BN into the following linear layer; weights out in bf16.
//   Wp[n,k] = bf16(W[n,k]*scale[k]);  bias[n] = sum_k W[n,k]*shift[k] (f32)
// ---------------------------------------------------------------------------
__global__ __launch_bounds__(256) void fold_bn(
    const float* __restrict__ W, const float* __restrict__ gamma,
    const float* __restrict__ beta, const float* __restrict__ mean,
    const float* __restrict__ var, ushort* __restrict__ Wp,
    float* __restrict__ bias, int K)
{
    int n = blockIdx.x;
    int tid = threadIdx.x;
    float acc = 0.f;
    for (int k = tid; k < K; k += 256) {
        float sc = gamma[k] * rsqrtf(var[k] + BN_EPS);
        float sh = beta[k] - mean[k] * sc;
        float w = W[(long)n * K + k];
        Wp[(long)n * K + k] = f2bf(w * sc);
        acc = fmaf(w, sh, acc);
    }
    __shared__ float red[256];
    red[tid] = acc;
    __syncthreads();
    for (int s = 128; s > 0; s >>= 1) {
        if (tid < s) red[tid] += red[tid + s];
        __syncthreads();
    }
    if (tid == 0) bias[n] = red[0];
}

// ---------------------------------------------------------------------------
__global__ __launch_bounds__(256) void f32_to_bf16(
    const float* __restrict__ x, ushort* __restrict__ y)
{
    long i = ((long)blockIdx.x * 256 + threadIdx.x) * 4;
    float4 v = *(const float4*)&x[i];
    ushort4 o = { f2bf(v.x), f2bf(v.y), f2bf(v.z), f2bf(v.w) };
    *(ushort4*)&y[i] = o;
}

// ---------------------------------------------------------------------------
// hT[b][d][k] = bf16(h[b][k][d]); 64x64 tiles via LDS.
// ---------------------------------------------------------------------------
__global__ __launch_bounds__(256) void transpose_bf16(
    const float* __restrict__ h, ushort* __restrict__ hT)
{
    __shared__ float tl[64][65];
    int b = blockIdx.z, k0 = blockIdx.y * 64, d0 = blockIdx.x * 64;
    int t = threadIdx.x, r = t >> 4, c = (t & 15) * 4;
    const float* hb = h + ((long)b * Tkc + k0) * Dc + d0;
    #pragma unroll
    for (int i = 0; i < 4; i++) {
        float4 v = *(const float4*)&hb[(long)(r + i * 16) * Dc + c];
        tl[r + i * 16][c + 0] = v.x; tl[r + i * 16][c + 1] = v.y;
        tl[r + i * 16][c + 2] = v.z; tl[r + i * 16][c + 3] = v.w;
    }
    __syncthreads();
    ushort* o = hT + ((long)b * Dc + d0) * Tkc + k0;
    #pragma unroll
    for (int i = 0; i < 4; i++) {
        int dr = r + i * 16;
        ushort4 ov = { f2bf(tl[c + 0][dr]), f2bf(tl[c + 1][dr]),
                       f2bf(tl[c + 2][dr]), f2bf(tl[c + 3][dr]) };
        *(ushort4*)&o[(long)dr * Tkc + c] = ov;
    }
}

// ---------------------------------------------------------------------------
// bf16 MFMA GEMM (NT): C[m,n] = sum_k A[m,k]*B[n,k] (+bias[n])
// A: Mx K (lda), B: N x K (ldb), both bf16 k-contiguous. 128x128 tile, BK=32,
// 256 threads = 4 waves in 2x2, each wave 64x64 via 4x4 mfma_f32_16x16x32_bf16.
// Staging: global_load_lds width 16, chunk-XOR swizzle so ds_read_b128 is
// <=2-way bank conflicted. Batched via blockIdx.z (z = hh*nB + bb).
// Output: f32 (Cf) or bf16 (Cb) selected by Cb != nullptr.
// ---------------------------------------------------------------------------
typedef __attribute__((address_space(1))) void gvoid;
typedef __attribute__((address_space(3))) void lvoid;

__global__ __launch_bounds__(256) void gemm_mfma(
    const ushort* __restrict__ A, const ushort* __restrict__ B,
    float* __restrict__ Cf, ushort* __restrict__ Cb,
    const float* __restrict__ bias,
    int K, int lda, int ldb, int ldc,
    long sAh, long sAb, long sBb, long sCh, long sCb, int nB)
{
    int z = blockIdx.z;
    int hh = z / nB, bb = z - hh * nB;
    A += hh * sAh + bb * sAb;
    B += bb * sBb;
    long coff = hh * sCh + bb * sCb;

    __shared__ ushort Als[128 * 32];
    __shared__ ushort Bls[128 * 32];

    int tid = threadIdx.x;
    int l = tid & 63, w = tid >> 6;
    int m0 = blockIdx.y * 128, n0 = blockIdx.x * 128;

    // staging: wave w covers chunks [(w*2+j)*64 + l], j=0,1 ; chunk=(row,slot)
    int L0 = (w * 2 + 0) * 64 + l;
    int L1 = (w * 2 + 1) * 64 + l;
    int am0 = L0 >> 2, ac0 = (L0 & 3) ^ ((am0 >> 1) & 3);
    int am1 = L1 >> 2, ac1 = (L1 & 3) ^ ((am1 >> 1) & 3);
    const ushort* gA0 = A + (long)(m0 + am0) * lda + ac0 * 8;
    const ushort* gA1 = A + (long)(m0 + am1) * lda + ac1 * 8;
    const ushort* gB0 = B + (long)(n0 + am0) * ldb + ac0 * 8;
    const ushort* gB1 = B + (long)(n0 + am1) * ldb + ac1 * 8;
    ushort* lA0 = &Als[(w * 2 + 0) * 512];   // wave-uniform LDS bases
    ushort* lA1 = &Als[(w * 2 + 1) * 512];
    ushort* lB0 = &Bls[(w * 2 + 0) * 512];
    ushort* lB1 = &Bls[(w * 2 + 1) * 512];

    int wm = (w >> 1) * 64, wn = (w & 1) * 64;
    int fr = l & 15, kc = l >> 4;

    // ds_read indices (ushort units) for the 4 m-tiles / 4 n-tiles
    int aidx[4], bidx[4];
    #pragma unroll
    for (int t = 0; t < 4; t++) {
        int ra = wm + t * 16 + fr;
        aidx[t] = (ra * 4 + (kc ^ ((ra >> 1) & 3))) * 8;
        int rb = wn + t * 16 + fr;
        bidx[t] = (rb * 4 + (kc ^ ((rb >> 1) & 3))) * 8;
    }

    f4v acc[4][4] = {};

    for (int k0 = 0; k0 < K; k0 += 32) {
        __builtin_amdgcn_global_load_lds((gvoid*)(gA0 + k0), (lvoid*)lA0, 16, 0, 0);
        __builtin_amdgcn_global_load_lds((gvoid*)(gA1 + k0), (lvoid*)lA1, 16, 0, 0);
        __builtin_amdgcn_global_load_lds((gvoid*)(gB0 + k0), (lvoid*)lB0, 16, 0, 0);
        __builtin_amdgcn_global_load_lds((gvoid*)(gB1 + k0), (lvoid*)lB1, 16, 0, 0);
        __syncthreads();

        s8v af[4], bfv[4];
        #pragma unroll
        for (int t = 0; t < 4; t++) af[t]  = *(const s8v*)&Als[aidx[t]];
        #pragma unroll
        for (int t = 0; t < 4; t++) bfv[t] = *(const s8v*)&Bls[bidx[t]];
        #pragma unroll
        for (int i = 0; i < 4; i++)
            #pragma unroll
            for (int j = 0; j < 4; j++)
                acc[i][j] = __builtin_amdgcn_mfma_f32_16x16x32_bf16(
                    af[i], bfv[j], acc[i][j], 0, 0, 0);
        __syncthreads();
    }

    // epilogue: D row = (l>>4)*4 + r, col = l&15
    #pragma unroll
    for (int i = 0; i < 4; i++) {
        #pragma unroll
        for (int j = 0; j < 4; j++) {
            int n = n0 + wn + j * 16 + fr;
            float bv = bias ? bias[n] : 0.f;
            #pragma unroll
            for (int r = 0; r < 4; r++) {
                int m = m0 + wm + i * 16 + kc * 4 + r;
                float v = acc[i][j][r] + bv;
                long off = coff + (long)m * ldc + n;
                if (Cb) Cb[off] = f2bf(v);
                else    Cf[off] = v;
            }
        }
    }
}

// ---------------------------------------------------------------------------
// In-place row softmax (rows of 1024 f32) + bf16 copy for the next GEMM.
// One wave per row, 4 rows per block.
// ---------------------------------------------------------------------------
__global__ __launch_bounds__(256) void softmax_rows(
    float* __restrict__ E, ushort* __restrict__ Abf)
{
    int wave = threadIdx.x >> 6;
    int lane = threadIdx.x & 63;
    long row = (long)blockIdx.x * 4 + wave;
    float4* rp = (float4*)(E + row * 1024);
    ushort* op = Abf + row * 1024;

    float4 v[4];
    float mx = -3.4e38f;
    #pragma unroll
    for (int i = 0; i < 4; i++) {
        v[i] = rp[lane + (i << 6)];
        mx = fmaxf(mx, fmaxf(fmaxf(v[i].x, v[i].y), fmaxf(v[i].z, v[i].w)));
    }
    #pragma unroll
    for (int o = 32; o > 0; o >>= 1) mx = fmaxf(mx, __shfl_xor(mx, o, 64));

    float sum = 0.f;
    #pragma unroll
    for (int i = 0; i < 4; i++) {
        v[i].x = __expf(v[i].x - mx);
        v[i].y = __expf(v[i].y - mx);
        v[i].z = __expf(v[i].z - mx);
        v[i].w = __expf(v[i].w - mx);
        sum += v[i].x + v[i].y + v[i].z + v[i].w;
    }
    #pragma unroll
    for (int o = 32; o > 0; o >>= 1) sum += __shfl_xor(sum, o, 64);

    float inv = 1.f / sum;
    #pragma unroll
    for (int i = 0; i < 4; i++) {
        v[i].x *= inv; v[i].y *= inv; v[i].z *= inv; v[i].w *= inv;
        rp[lane + (i << 6)] = v[i];
        ushort4 ov = { f2bf(v[i].x), f2bf(v[i].y), f2bf(v[i].z), f2bf(v[i].w) };
        *(ushort4*)&op[(lane + (i << 6)) * 4] = ov;
    }
}

// ---------------------------------------------------------------------------
extern "C" void kernel_launch(void* const* d_in, const int* in_sizes, int n_in,
                              void* d_out, int out_size, void* d_ws, size_t ws_size,
                              hipStream_t stream)
{
    const float* s     = (const float*)d_in[0];
    const float* h     = (const float*)d_in[1];
    const float* phi_g = (const float*)d_in[2];
    const float* phi_b = (const float*)d_in[3];
    const float* phi_m = (const float*)d_in[4];
    const float* phi_v = (const float*)d_in[5];
    const float* W_phi = (const float*)d_in[6];
    const float* psi_g = (const float*)d_in[7];
    const float* psi_b = (const float*)d_in[8];
    const float* psi_m = (const float*)d_in[9];
    const float* psi_v = (const float*)d_in[10];
    const float* W_psi = (const float*)d_in[11];
    const float* red_g = (const float*)d_in[12];
    const float* red_b = (const float*)d_in[13];
    const float* red_m = (const float*)d_in[14];
    const float* red_v = (const float*)d_in[15];
    const float* W_red = (const float*)d_in[16];

    float* out_a = (float*)d_out;                         // (H,B,Tq,Tk) f32
    float* out_c = out_a + (long)Hc * Bc * Tq * Tkc;      // (B,Tq,D)  f32

    char* p = (char*)d_ws;
    ushort* Wphi_b = (ushort*)p;  p += (long)2048 * 512 * 2;
    ushort* Wpsi_b = (ushort*)p;  p += (long)512 * 512 * 2;
    ushort* Wred_b = (ushort*)p;  p += (long)512 * 2048 * 2;
    float* bias_phi = (float*)p;  p += 2048 * 4;
    float* bias_psi = (float*)p;  p += 512 * 4;
    float* bias_red = (float*)p;  p += 512 * 4;
    ushort* s_bf  = (ushort*)p;   p += (long)8192 * 512 * 2;    // 8 MB
    ushort* h_bf  = (ushort*)p;   p += (long)32768 * 512 * 2;   // 32 MB
    ushort* hT_bf = (ushort*)p;   p += (long)32768 * 512 * 2;   // 32 MB (b,d,k)
    ushort* ms_bf = (ushort*)p;   p += (long)8192 * 2048 * 2;   // 32 MB
    ushort* mh_bf = (ushort*)p;   p += (long)32768 * 512 * 2;   // 32 MB
    ushort* a_bf  = ms_bf;   // 64 MB alias over ms+mh (dead after gemm3)
    ushort* ctx_bf = s_bf;   // 32 MB alias over s_bf+h_bf (dead after gemm2)

    // 1) BN folds (bf16 weights + f32 bias)
    fold_bn<<<2048, 256, 0, stream>>>(W_phi, phi_g, phi_b, phi_m, phi_v, Wphi_b, bias_phi, 512);
    fold_bn<<<512,  256, 0, stream>>>(W_psi, psi_g, psi_b, psi_m, psi_v, Wpsi_b, bias_psi, 512);
    fold_bn<<<512,  256, 0, stream>>>(W_red, red_g, red_b, red_m, red_v, Wred_b, bias_red, 2048);

    // 2) activation converts
    f32_to_bf16<<<4096,  256, 0, stream>>>(s, s_bf);       // 8192*512
    f32_to_bf16<<<16384, 256, 0, stream>>>(h, h_bf);       // 32768*512
    transpose_bf16<<<dim3(8, 16, 32), 256, 0, stream>>>(h, hT_bf);

    // 3) ms = s @ Wphi^T + bias -> bf16 (8192 x 2048, K=512)
    gemm_mfma<<<dim3(16, 64, 1), 256, 0, stream>>>(
        s_bf, Wphi_b, nullptr, ms_bf, bias_phi,
        512, 512, 512, 2048, 0, 0, 0, 0, 0, 1);

    // 4) mh = h @ Wpsi^T + bias -> bf16 (32768 x 512, K=512)
    gemm_mfma<<<dim3(4, 256, 1), 256, 0, stream>>>(
        h_bf, Wpsi_b, nullptr, mh_bf, bias_psi,
        512, 512, 512, 512, 0, 0, 0, 0, 0, 1);

    // 5) e[hh,bb] = ms4 . mh^T -> f32 out_a (128 batches of 256x1024, K=512)
    gemm_mfma<<<dim3(8, 2, Hc * Bc), 256, 0, stream>>>(
        ms_bf, mh_bf, out_a, nullptr, nullptr,
        512, 2048, 512, 1024,
        /*sAh*/ 512, /*sAb*/ (long)Tq * 2048,
        /*sBb*/ (long)Tkc * 512,
        /*sCh*/ (long)Bc * Tq * Tkc, /*sCb*/ (long)Tq * Tkc, Bc);

    // 6) softmax rows (in-place f32) + bf16 copy
    softmax_rows<<<(Hc * Bc * Tq) / 4, 256, 0, stream>>>(out_a, a_bf);

    // 7) ctx[bb,q,hh*512+d] = a . h  via NT with hT (128 batches 256x512, K=1024)
    gemm_mfma<<<dim3(4, 2, Hc * Bc), 256, 0, stream>>>(
        a_bf, hT_bf, nullptr, ctx_bf, nullptr,
        1024, 1024, 1024, 2048,
        /*sAh*/ (long)Bc * Tq * Tkc, /*sAb*/ (long)Tq * Tkc,
        /*sBb*/ (long)Dc * Tkc,
        /*sCh*/ 512, /*sCb*/ (long)Tq * 2048, Bc);

    // 8) c = ctx @ Wred^T + bias -> f32 (8192 x 512, K=2048)
    gemm_mfma<<<dim3(4, 64, 1), 256, 0, stream>>>(
        ctx_bf, Wred_b, out_c, nullptr, bias_red,
        2048, 2048, 2048, 512, 0, 0, 0, 0, 0, 1);
}

// Round 3
// 535.906 us; speedup vs baseline: 3.4235x; 1.1559x over previous
//
#include <hip/hip_runtime.h>

typedef short s8v __attribute__((ext_vector_type(8)));
typedef float f4v __attribute__((ext_vector_type(4)));

static constexpr int Bc = 32, Tq = 256, Tkc = 1024, Dc = 512, Hc = 4;
static constexpr float BN_EPS = 1e-5f;

__device__ inline ushort f2bf(float x) {
    union { float f; unsigned int u; } v; v.f = x;
    unsigned int r = v.u + 0x7fff + ((v.u >> 16) & 1);   // RNE
    return (ushort)(r >> 16);
}

// ---------------------------------------------------------------------------
// Fold eval-mode BN into the following linear layer; weights out in bf16.
// ---------------------------------------------------------------------------
__global__ __launch_bounds__(256) void fold_bn(
    const float* __restrict__ W, const float* __restrict__ gamma,
    const float* __restrict__ beta, const float* __restrict__ mean,
    const float* __restrict__ var, ushort* __restrict__ Wp,
    float* __restrict__ bias, int K)
{
    int n = blockIdx.x;
    int tid = threadIdx.x;
    float acc = 0.f;
    for (int k = tid; k < K; k += 256) {
        float sc = gamma[k] * rsqrtf(var[k] + BN_EPS);
        float sh = beta[k] - mean[k] * sc;
        float w = W[(long)n * K + k];
        Wp[(long)n * K + k] = f2bf(w * sc);
        acc = fmaf(w, sh, acc);
    }
    __shared__ float red[256];
    red[tid] = acc;
    __syncthreads();
    for (int s = 128; s > 0; s >>= 1) {
        if (tid < s) red[tid] += red[tid + s];
        __syncthreads();
    }
    if (tid == 0) bias[n] = red[0];
}

// ---------------------------------------------------------------------------
__global__ __launch_bounds__(256) void f32_to_bf16(
    const float* __restrict__ x, ushort* __restrict__ y)
{
    long i = ((long)blockIdx.x * 256 + threadIdx.x) * 4;
    float4 v = *(const float4*)&x[i];
    ushort4 o = { f2bf(v.x), f2bf(v.y), f2bf(v.z), f2bf(v.w) };
    *(ushort4*)&y[i] = o;
}

// ---------------------------------------------------------------------------
// Fused: h_bf[b][k][d] = bf16(h[b][k][d]) AND hT[b][d][k] = bf16(h[b][k][d])
// ---------------------------------------------------------------------------
__global__ __launch_bounds__(256) void conv_h(
    const float* __restrict__ h, ushort* __restrict__ h_bf,
    ushort* __restrict__ hT)
{
    __shared__ float tl[64][65];
    int b = blockIdx.z, k0 = blockIdx.y * 64, d0 = blockIdx.x * 64;
    int t = threadIdx.x, r = t >> 4, c = (t & 15) * 4;
    const float* hb = h + ((long)b * Tkc + k0) * Dc + d0;
    ushort* sb = h_bf + ((long)b * Tkc + k0) * Dc + d0;
    #pragma unroll
    for (int i = 0; i < 4; i++) {
        int rr = r + i * 16;
        float4 v = *(const float4*)&hb[(long)rr * Dc + c];
        tl[rr][c + 0] = v.x; tl[rr][c + 1] = v.y;
        tl[rr][c + 2] = v.z; tl[rr][c + 3] = v.w;
        ushort4 sv = { f2bf(v.x), f2bf(v.y), f2bf(v.z), f2bf(v.w) };
        *(ushort4*)&sb[(long)rr * Dc + c] = sv;
    }
    __syncthreads();
    ushort* o = hT + ((long)b * Dc + d0) * Tkc + k0;
    #pragma unroll
    for (int i = 0; i < 4; i++) {
        int dr = r + i * 16;
        ushort4 ov = { f2bf(tl[c + 0][dr]), f2bf(tl[c + 1][dr]),
                       f2bf(tl[c + 2][dr]), f2bf(tl[c + 3][dr]) };
        *(ushort4*)&o[(long)dr * Tkc + c] = ov;
    }
}

// ---------------------------------------------------------------------------
// out_c[m][n] = bias[n]  (split-K atomic accumulation target)
// ---------------------------------------------------------------------------
__global__ __launch_bounds__(256) void init_c(
    float* __restrict__ C, const float* __restrict__ bias)
{
    long i = (long)blockIdx.x * 256 + threadIdx.x;   // float4 index
    int n4 = (int)(i & 127);
    float4 b = ((const float4*)bias)[n4];
    ((float4*)C)[i] = b;
}

// ---------------------------------------------------------------------------
// bf16 MFMA GEMM (NT): C[m,n] = sum_k A[m,k]*B[n,k] (+bias[n])
// 128x128 tile, BK=64 (32 MFMA per barrier window), 4 waves in 2x2.
// 1D grid, decode: z = bx & ((1<<zbits)-1)  [XCD co-location: same-batch
// blocks share id mod 8], j = bx >> zbits, x = j & (2^nxs-1), y = j >> nxs.
// z -> (hh = z/nB, bb = z%nB). Output: atomic f32 / plain f32 / bf16.
// ---------------------------------------------------------------------------
typedef __attribute__((address_space(1))) void gvoid;
typedef __attribute__((address_space(3))) void lvoid;

__global__ __launch_bounds__(256, 4) void gemm_mfma(
    const ushort* __restrict__ A, const ushort* __restrict__ B,
    float* __restrict__ Cf, ushort* __restrict__ Cb,
    const float* __restrict__ bias, int atom,
    int K, int lda, int ldb, int ldc,
    long sAh, long sAb, long sBh, long sBb, long sCh, long sCb,
    int nB, int nxs, int zbits)
{
    int bx = blockIdx.x;
    int z = bx & ((1 << zbits) - 1);
    int j2 = bx >> zbits;
    int gx = j2 & ((1 << nxs) - 1);
    int gy = j2 >> nxs;

    int hh = z / nB, bb = z - hh * nB;
    A += hh * sAh + bb * sAb;
    B += hh * sBh + bb * sBb;
    long coff = hh * sCh + bb * sCb;

    __shared__ ushort Als[128 * 64];
    __shared__ ushort Bls[128 * 64];

    int tid = threadIdx.x;
    int l = tid & 63, w = tid >> 6;
    int m0 = gy * 128, n0 = gx * 128;

    // staging: wave w stages chunks [(w*4+j)*64 + l]; chunk 16B; row m=L>>3,
    // stored slot c=L&7 holds global k-chunk c^((m>>1)&7)  (bank swizzle)
    const ushort* gA[4]; const ushort* gB[4];
    ushort* lA[4]; ushort* lB[4];
    #pragma unroll
    for (int j = 0; j < 4; j++) {
        int L = (w * 4 + j) * 64 + l;
        int m = L >> 3, c = L & 7;
        int kof = (c ^ ((m >> 1) & 7)) * 8;
        gA[j] = A + (long)(m0 + m) * lda + kof;
        gB[j] = B + (long)(n0 + m) * ldb + kof;
        lA[j] = &Als[(w * 4 + j) * 512];
        lB[j] = &Bls[(w * 4 + j) * 512];
    }

    int wm = (w >> 1) * 64, wn = (w & 1) * 64;
    int fr = l & 15, kc = l >> 4;

    int aidx[2][4], bidx[2][4];
    #pragma unroll
    for (int kk = 0; kk < 2; kk++)
        #pragma unroll
        for (int t = 0; t < 4; t++) {
            int ra = wm + t * 16 + fr;
            aidx[kk][t] = (ra * 8 + ((kk * 4 + kc) ^ ((ra >> 1) & 7))) * 8;
            int rb = wn + t * 16 + fr;
            bidx[kk][t] = (rb * 8 + ((kk * 4 + kc) ^ ((rb >> 1) & 7))) * 8;
        }

    f4v acc[4][4] = {};

    for (int k0 = 0; k0 < K; k0 += 64) {
        #pragma unroll
        for (int j = 0; j < 4; j++) {
            __builtin_amdgcn_global_load_lds((gvoid*)(gA[j] + k0), (lvoid*)lA[j], 16, 0, 0);
            __builtin_amdgcn_global_load_lds((gvoid*)(gB[j] + k0), (lvoid*)lB[j], 16, 0, 0);
        }
        __syncthreads();
        #pragma unroll
        for (int kk = 0; kk < 2; kk++) {
            s8v af[4], bfv[4];
            #pragma unroll
            for (int t = 0; t < 4; t++) af[t]  = *(const s8v*)&Als[aidx[kk][t]];
            #pragma unroll
            for (int t = 0; t < 4; t++) bfv[t] = *(const s8v*)&Bls[bidx[kk][t]];
            #pragma unroll
            for (int i = 0; i < 4; i++)
                #pragma unroll
                for (int jj = 0; jj < 4; jj++)
                    acc[i][jj] = __builtin_amdgcn_mfma_f32_16x16x32_bf16(
                        af[i], bfv[jj], acc[i][jj], 0, 0, 0);
        }
        __syncthreads();
    }

    // epilogue: D row = (l>>4)*4 + r, col = l&15
    #pragma unroll
    for (int i = 0; i < 4; i++) {
        #pragma unroll
        for (int jj = 0; jj < 4; jj++) {
            int n = n0 + wn + jj * 16 + fr;
            float bv = bias ? bias[n] : 0.f;
            #pragma unroll
            for (int r = 0; r < 4; r++) {
                int m = m0 + wm + i * 16 + kc * 4 + r;
                float v = acc[i][jj][r] + bv;
                long off = coff + (long)m * ldc + n;
                if (atom)    atomicAdd(&Cf[off], v);
                else if (Cb) Cb[off] = f2bf(v);
                else         Cf[off] = v;
            }
        }
    }
}

// ---------------------------------------------------------------------------
// In-place row softmax (rows of 1024 f32) + bf16 copy.
// ---------------------------------------------------------------------------
__global__ __launch_bounds__(256) void softmax_rows(
    float* __restrict__ E, ushort* __restrict__ Abf)
{
    int wave = threadIdx.x >> 6;
    int lane = threadIdx.x & 63;
    long row = (long)blockIdx.x * 4 + wave;
    float4* rp = (float4*)(E + row * 1024);
    ushort* op = Abf + row * 1024;

    float4 v[4];
    float mx = -3.4e38f;
    #pragma unroll
    for (int i = 0; i < 4; i++) {
        v[i] = rp[lane + (i << 6)];
        mx = fmaxf(mx, fmaxf(fmaxf(v[i].x, v[i].y), fmaxf(v[i].z, v[i].w)));
    }
    #pragma unroll
    for (int o = 32; o > 0; o >>= 1) mx = fmaxf(mx, __shfl_xor(mx, o, 64));

    float sum = 0.f;
    #pragma unroll
    for (int i = 0; i < 4; i++) {
        v[i].x = __expf(v[i].x - mx);
        v[i].y = __expf(v[i].y - mx);
        v[i].z = __expf(v[i].z - mx);
        v[i].w = __expf(v[i].w - mx);
        sum += v[i].x + v[i].y + v[i].z + v[i].w;
    }
    #pragma unroll
    for (int o = 32; o > 0; o >>= 1) sum += __shfl_xor(sum, o, 64);

    float inv = 1.f / sum;
    #pragma unroll
    for (int i = 0; i < 4; i++) {
        v[i].x *= inv; v[i].y *= inv; v[i].z *= inv; v[i].w *= inv;
        rp[lane + (i << 6)] = v[i];
        ushort4 ov = { f2bf(v[i].x), f2bf(v[i].y), f2bf(v[i].z), f2bf(v[i].w) };
        *(ushort4*)&op[(lane + (i << 6)) * 4] = ov;
    }
}

// ---------------------------------------------------------------------------
extern "C" void kernel_launch(void* const* d_in, const int* in_sizes, int n_in,
                              void* d_out, int out_size, void* d_ws, size_t ws_size,
                              hipStream_t stream)
{
    const float* s     = (const float*)d_in[0];
    const float* h     = (const float*)d_in[1];
    const float* phi_g = (const float*)d_in[2];
    const float* phi_b = (const float*)d_in[3];
    const float* phi_m = (const float*)d_in[4];
    const float* phi_v = (const float*)d_in[5];
    const float* W_phi = (const float*)d_in[6];
    const float* psi_g = (const float*)d_in[7];
    const float* psi_b = (const float*)d_in[8];
    const float* psi_m = (const float*)d_in[9];
    const float* psi_v = (const float*)d_in[10];
    const float* W_psi = (const float*)d_in[11];
    const float* red_g = (const float*)d_in[12];
    const float* red_b = (const float*)d_in[13];
    const float* red_m = (const float*)d_in[14];
    const float* red_v = (const float*)d_in[15];
    const float* W_red = (const float*)d_in[16];

    float* out_a = (float*)d_out;                         // (H,B,Tq,Tk) f32
    float* out_c = out_a + (long)Hc * Bc * Tq * Tkc;      // (B,Tq,D)  f32

    char* p = (char*)d_ws;
    ushort* Wphi_b = (ushort*)p;  p += (long)2048 * 512 * 2;
    ushort* Wpsi_b = (ushort*)p;  p += (long)512 * 512 * 2;
    ushort* Wred_b = (ushort*)p;  p += (long)512 * 2048 * 2;
    float* bias_phi = (float*)p;  p += 2048 * 4;
    float* bias_psi = (float*)p;  p += 512 * 4;
    float* bias_red = (float*)p;  p += 512 * 4;
    ushort* s_bf  = (ushort*)p;   p += (long)8192 * 512 * 2;
    ushort* h_bf  = (ushort*)p;   p += (long)32768 * 512 * 2;
    ushort* hT_bf = (ushort*)p;   p += (long)32768 * 512 * 2;
    ushort* ms_bf = (ushort*)p;   p += (long)8192 * 2048 * 2;
    ushort* mh_bf = (ushort*)p;   p += (long)32768 * 512 * 2;
    ushort* a_bf  = ms_bf;   // alias (ms+mh dead after scores GEMM)
    ushort* ctx_bf = s_bf;   // alias (s_bf+h_bf dead after their GEMMs)

    // 1) BN folds
    fold_bn<<<2048, 256, 0, stream>>>(W_phi, phi_g, phi_b, phi_m, phi_v, Wphi_b, bias_phi, 512);
    fold_bn<<<512,  256, 0, stream>>>(W_psi, psi_g, psi_b, psi_m, psi_v, Wpsi_b, bias_psi, 512);
    fold_bn<<<512,  256, 0, stream>>>(W_red, red_g, red_b, red_m, red_v, Wred_b, bias_red, 2048);

    // 2) activation converts (+ c-output bias init for split-K atomics)
    f32_to_bf16<<<4096, 256, 0, stream>>>(s, s_bf);
    conv_h<<<dim3(8, 16, 32), 256, 0, stream>>>(h, h_bf, hT_bf);
    init_c<<<4096, 256, 0, stream>>>(out_c, bias_red);

    // 3) ms = s @ Wphi^T + bias -> bf16 (8192 x 2048, K=512), grid 16x64
    gemm_mfma<<<16 * 64, 256, 0, stream>>>(
        s_bf, Wphi_b, nullptr, ms_bf, bias_phi, 0,
        512, 512, 512, 2048, 0, 0, 0, 0, 0, 0, 1, /*nxs*/4, /*zbits*/0);

    // 4) mh = h @ Wpsi^T + bias -> bf16 (32768 x 512, K=512), grid 4x256
    gemm_mfma<<<4 * 256, 256, 0, stream>>>(
        h_bf, Wpsi_b, nullptr, mh_bf, bias_psi, 0,
        512, 512, 512, 512, 0, 0, 0, 0, 0, 0, 1, /*nxs*/2, /*zbits*/0);

    // 5) e = ms4 . mh^T -> f32 out_a (128 batches of 256x1024, K=512), 8x2x128
    gemm_mfma<<<8 * 2 * 128, 256, 0, stream>>>(
        ms_bf, mh_bf, out_a, nullptr, nullptr, 0,
        512, 2048, 512, 1024,
        /*sAh*/ 512, /*sAb*/ (long)Tq * 2048,
        /*sBh*/ 0, /*sBb*/ (long)Tkc * 512,
        /*sCh*/ (long)Bc * Tq * Tkc, /*sCb*/ (long)Tq * Tkc,
        Bc, /*nxs*/3, /*zbits*/7);

    // 6) softmax rows + bf16 copy
    softmax_rows<<<(Hc * Bc * Tq) / 4, 256, 0, stream>>>(out_a, a_bf);

    // 7) ctx = a . h (via hT, NT) -> bf16 (128 batches 256x512, K=1024), 4x2x128
    gemm_mfma<<<4 * 2 * 128, 256, 0, stream>>>(
        a_bf, hT_bf, nullptr, ctx_bf, nullptr, 0,
        1024, 1024, 1024, 2048,
        /*sAh*/ (long)Bc * Tq * Tkc, /*sAb*/ (long)Tq * Tkc,
        /*sBh*/ 0, /*sBb*/ (long)Dc * Tkc,
        /*sCh*/ 512, /*sCb*/ (long)Tq * 2048,
        Bc, /*nxs*/2, /*zbits*/7);

    // 8) c += ctx @ Wred^T (split-K x4, atomic f32; bias pre-initialized)
    //    grid 4x64x4chunks; chunk = z: A/B advance 512 in k
    gemm_mfma<<<4 * 64 * 4, 256, 0, stream>>>(
        ctx_bf, Wred_b, out_c, nullptr, nullptr, 1,
        512, 2048, 2048, 512,
        /*sAh*/ 512, /*sAb*/ 0,
        /*sBh*/ 512, /*sBb*/ 0,
        /*sCh*/ 0, /*sCb*/ 0,
        1, /*nxs*/2, /*zbits*/2);
}